// Round 8
// baseline (273.502 us; speedup 1.0000x reference)
//
#include <hip/hip_runtime.h>
#include <math.h>

#define TT    4096
#define NFFT  8192
#define LOGN  13
#define NTHR  512
#define BS    128
#define NTASK 576
#define BUFSZ (NFFT + NFFT/8)   // prep/fallback buffer (additive swizzle)

__device__ __forceinline__ float2 cmulf(float2 u, float2 v){
  return make_float2(u.x*v.x - u.y*v.y, u.x*v.y + u.y*v.x);
}
__device__ __forceinline__ float2 cadd(float2 a, float2 b){ return make_float2(a.x+b.x, a.y+b.y); }
__device__ __forceinline__ float2 csub(float2 a, float2 b){ return make_float2(a.x-b.x, a.y-b.y); }
__device__ __forceinline__ float2 cmuli (float2 a){ return make_float2(-a.y,  a.x); }
__device__ __forceinline__ float2 cmulni(float2 a){ return make_float2( a.y, -a.x); }
__device__ __forceinline__ float2 csq(float2 a){ return make_float2(a.x*a.x - a.y*a.y, 2.f*a.x*a.y); }

// prep/fallback LDS accessor (additive swizzle)
__device__ __forceinline__ float2& BREF(float2* b, int i){ return b[i + (i>>3)]; }
// convk5 LDS swizzle: XOR fold bits 4-7 into 0-3 (bijective, conflict-free for
// stride 1/2/32/512 float2 access patterns)
#define SWZ(p) ((p) ^ (((p)>>4)&15))

#define DEF_C8  const float2 C8[8]  = { {1.f,0.f},{0.9238795325f,-0.3826834324f},{0.7071067812f,-0.7071067812f},{0.3826834324f,-0.9238795325f},{0.f,-1.f},{-0.3826834324f,-0.9238795325f},{-0.7071067812f,-0.7071067812f},{-0.9238795325f,-0.3826834324f} }
#define DEF_CC8 const float2 CC8[8] = { {1.f,0.f},{0.9238795325f, 0.3826834324f},{0.7071067812f, 0.7071067812f},{0.3826834324f, 0.9238795325f},{0.f, 1.f},{-0.3826834324f, 0.9238795325f},{-0.7071067812f, 0.7071067812f},{-0.9238795325f, 0.3826834324f} }

constexpr int ctz_c(int v){ int c=0; while(!(v&1)){ v>>=1; c++; } return c; }

// ========================= register radix-16 cores =========================
// fwd DIF stages s = 8s,4s,2s,s on v[16] (positions c + sigma*k), after the
// first (8-sigma) stage has been applied by the caller. u2 = exp(-i*pi*c/(4sig)).
__device__ __forceinline__ void rad16_fwd_tail(float2* v, float2 u2){
  DEF_C8;
  float2 u3 = csq(u2), u4 = csq(u3);
  #pragma unroll
  for (int g=0; g<16; g+=8)
    #pragma unroll
    for (int t=0;t<4;t++){
      float2 a=v[g+t], b=v[g+t+4];
      v[g+t]=cadd(a,b);
      v[g+t+4]=cmulf(csub(a,b), cmulf(u2, C8[2*t]));
    }
  #pragma unroll
  for (int g=0; g<16; g+=4)
    #pragma unroll
    for (int t=0;t<2;t++){
      float2 a=v[g+t], b=v[g+t+2];
      v[g+t]=cadd(a,b);
      v[g+t+2]=cmulf(csub(a,b), cmulf(u3, C8[4*t]));
    }
  #pragma unroll
  for (int g=0; g<16; g+=2){
    float2 a=v[g], b=v[g+1];
    v[g]=cadd(a,b);
    v[g+1]=cmulf(csub(a,b), u4);
  }
}

// full 4-stage fwd radix-16; u1 = exp(-i*pi*c/(8*sigma))
__device__ __forceinline__ void rad16_fwd(float2* v, float2 u1){
  DEF_C8;
  #pragma unroll
  for (int t=0;t<8;t++){
    float2 a=v[t], b=v[t+8];
    v[t]=cadd(a,b);
    v[t+8]=cmulf(csub(a,b), cmulf(u1, C8[t]));
  }
  rad16_fwd_tail(v, csq(u1));
}

// inverse (transpose-conjugate) 4-stage radix-16, stages s = sig,2sig,4sig,8sig;
// u1c = exp(+i*pi*c/(8*sigma))
__device__ __forceinline__ void rad16_inv(float2* v, float2 u1c){
  DEF_CC8;
  float2 u2c = csq(u1c), u3c = csq(u2c), u4c = csq(u3c);
  #pragma unroll
  for (int g=0; g<16; g+=2){
    float2 b = cmulf(v[g+1], u4c);
    float2 a = v[g];
    v[g]=cadd(a,b); v[g+1]=csub(a,b);
  }
  #pragma unroll
  for (int g=0; g<16; g+=4)
    #pragma unroll
    for (int t=0;t<2;t++){
      float2 b = cmulf(v[g+t+2], cmulf(u3c, CC8[4*t]));
      float2 a = v[g+t];
      v[g+t]=cadd(a,b); v[g+t+2]=csub(a,b);
    }
  #pragma unroll
  for (int g=0; g<16; g+=8)
    #pragma unroll
    for (int t=0;t<4;t++){
      float2 b = cmulf(v[g+t+4], cmulf(u2c, CC8[2*t]));
      float2 a = v[g+t];
      v[g+t]=cadd(a,b); v[g+t+4]=csub(a,b);
    }
  #pragma unroll
  for (int t=0;t<8;t++){
    float2 b = cmulf(v[t+8], cmulf(u1c, CC8[t]));
    float2 a = v[t];
    v[t]=cadd(a,b); v[t+8]=csub(a,b);
  }
}

// last inverse pass: stages 512,1024,2048 full; stage 4096 lo-outputs only.
// u1c = exp(+i*pi*c/4096); y[t] = output at position c + 512*t, t<8.
__device__ __forceinline__ void rad16_inv_last(float2* v, float2 u1c, float2* y){
  DEF_CC8;
  float2 u2c = csq(u1c), u3c = csq(u2c), u4c = csq(u3c);
  #pragma unroll
  for (int g=0; g<16; g+=2){
    float2 b = cmulf(v[g+1], u4c);
    float2 a = v[g];
    v[g]=cadd(a,b); v[g+1]=csub(a,b);
  }
  #pragma unroll
  for (int g=0; g<16; g+=4)
    #pragma unroll
    for (int t=0;t<2;t++){
      float2 b = cmulf(v[g+t+2], cmulf(u3c, CC8[4*t]));
      float2 a = v[g+t];
      v[g+t]=cadd(a,b); v[g+t+2]=csub(a,b);
    }
  #pragma unroll
  for (int g=0; g<16; g+=8)
    #pragma unroll
    for (int t=0;t<4;t++){
      float2 b = cmulf(v[g+t+4], cmulf(u2c, CC8[2*t]));
      float2 a = v[g+t];
      v[g+t]=cadd(a,b); v[g+t+4]=csub(a,b);
    }
  #pragma unroll
  for (int t=0;t<8;t++)
    y[t] = cadd(v[t], cmulf(v[t+8], cmulf(u1c, CC8[t])));
}

// one inverse transform of (zreg .* H): P1'(product + s=1, own positions),
// P2'(sigma=2), P3'(sigma=32), P4'(sigma=512, outputs to y[8]).
template<bool FIRST>
__device__ __forceinline__ void inv16(float2* buf, int tid,
                                      const float2* zreg,
                                      const float2* __restrict__ H,
                                      float2* y){
  if (!FIRST) __syncthreads();          // prior P4' reads complete
  {
    float2 v[16];
    const float2* Hp = H + 16*tid;
    #pragma unroll
    for (int j=0;j<16;j++) v[j] = cmulf(zreg[j], Hp[j]);
    #pragma unroll
    for (int g=0; g<16; g+=2){
      float2 a=v[g], b=v[g+1];
      v[g]=cadd(a,b); v[g+1]=csub(a,b);
    }
    #pragma unroll
    for (int j=0;j<16;j++) buf[SWZ(16*tid + j)] = v[j];
  }
  __syncthreads();
  {
    float2 v[16];
    int base = 32*(tid>>1), c = tid&1;
    #pragma unroll
    for (int t=0;t<16;t++) v[t] = buf[SWZ(base + c + 2*t)];
    float2 u1c = c ? make_float2(0.9807852804f, 0.1950903220f) : make_float2(1.f, 0.f);
    rad16_inv(v, u1c);
    #pragma unroll
    for (int t=0;t<16;t++) buf[SWZ(base + c + 2*t)] = v[t];
  }
  __syncthreads();
  {
    float2 v[16];
    int base = 512*(tid>>5), c = tid&31;
    #pragma unroll
    for (int t=0;t<16;t++) v[t] = buf[SWZ(base + c + 32*t)];
    float sn, cs; __sincosf(3.14159265358979f*(float)c/256.f, &sn, &cs);
    rad16_inv(v, make_float2(cs, sn));
    #pragma unroll
    for (int t=0;t<16;t++) buf[SWZ(base + c + 32*t)] = v[t];
  }
  __syncthreads();
  {
    float2 v[16];
    #pragma unroll
    for (int t=0;t<16;t++) v[t] = buf[SWZ(tid + 512*t)];
    float sn, cs; __sincosf(3.14159265358979f*(float)tid/4096.f, &sn, &cs);
    rad16_inv_last(v, make_float2(cs, sn), y);
  }
}

// =================== legacy fused radix-4 passes (prep) ====================
template<int S>
__device__ __forceinline__ void fwd_pass(float2* buf, int tid){
  constexpr int LS = ctz_c(S);
  const float nis = -3.14159265358979f / (2.0f * (float)S);
  #pragma unroll
  for (int r = 0; r < (NFFT/4)/NTHR; ++r){
    int j   = tid + NTHR*r;
    int off = j & (S-1);
    int i0  = ((j >> LS) << (LS+2)) + off;
    float2 a = BREF(buf,i0), b = BREF(buf,i0+S), c = BREF(buf,i0+2*S), d = BREF(buf,i0+3*S);
    float sn, cs; __sincosf(nis*(float)off, &sn, &cs);
    float2 wA = make_float2(cs, sn);
    float2 wB = make_float2(cs*cs - sn*sn, 2.f*cs*sn);
    float2 w3 = cmulf(wA, wB);
    float2 s02 = cadd(a,c), d02 = csub(a,c);
    float2 s13 = cadd(b,d), d13 = csub(b,d);
    BREF(buf,i0)     = cadd(s02, s13);
    BREF(buf,i0+S)   = cmulf(csub(s02, s13), wB);
    BREF(buf,i0+2*S) = cmulf(wA, cadd(d02, cmulni(d13)));
    BREF(buf,i0+3*S) = cmulf(w3, cadd(d02, cmuli (d13)));
  }
}

__device__ __forceinline__ void fwd_final8(float2* buf, int tid){
  const float R2 = 0.70710678118654752f;
  #pragma unroll
  for (int r = 0; r < (NFFT/8)/NTHR; ++r){
    int m = tid + NTHR*r;
    float2 v[8];
    #pragma unroll
    for (int l=0;l<8;l++) v[l] = BREF(buf,8*m+l);
    { float2 t = csub(v[0], v[4]); v[0] = cadd(v[0], v[4]); v[4] = t; }
    { float2 t = csub(v[1], v[5]); v[1] = cadd(v[1], v[5]); v[5] = cmulf(t, make_float2(R2, -R2)); }
    { float2 t = csub(v[2], v[6]); v[2] = cadd(v[2], v[6]); v[6] = cmulni(t); }
    { float2 t = csub(v[3], v[7]); v[3] = cadd(v[3], v[7]); v[7] = cmulf(t, make_float2(-R2, -R2)); }
    #pragma unroll
    for (int base = 0; base < 8; base += 4){
      { float2 t = csub(v[base],   v[base+2]); v[base]   = cadd(v[base],   v[base+2]); v[base+2] = t; }
      { float2 t = csub(v[base+1], v[base+3]); v[base+1] = cadd(v[base+1], v[base+3]); v[base+3] = cmulni(t); }
    }
    #pragma unroll
    for (int p = 0; p < 8; p += 2){ float2 t = csub(v[p], v[p+1]); v[p] = cadd(v[p], v[p+1]); v[p+1] = t; }
    #pragma unroll
    for (int l=0;l<8;l++) BREF(buf,8*m+l) = v[l];
  }
}

// ---------------- Rodrigues rotation from skew axis
__device__ __forceinline__ void rot3(float ax, float ay, float az, float* R){
  float th2 = ax*ax + ay*ay + az*az;
  float s1, s2;
  if (th2 < 1e-8f){
    s1 = 1.f - th2*(1.f/6.f);
    s2 = 0.5f - th2*(1.f/24.f);
  } else {
    float th = sqrtf(th2);
    float sn = sinf(th);
    s1 = sn / th;
    float sh = sinf(0.5f*th);
    s2 = 2.f*sh*sh / th2;
  }
  R[0] = 1.f - s2*(ay*ay+az*az);
  R[1] = -s1*az + s2*ax*ay;
  R[2] =  s1*ay + s2*ax*az;
  R[3] =  s1*az + s2*ax*ay;
  R[4] = 1.f - s2*(ax*ax+az*az);
  R[5] = -s1*ax + s2*ay*az;
  R[6] = -s1*ay + s2*ax*az;
  R[7] =  s1*ax + s2*ay*az;
  R[8] = 1.f - s2*(ax*ax+ay*ay);
}

__device__ __forceinline__ void mm3(const float* A, const float* B, float* C){
  #pragma unroll
  for (int i=0;i<3;i++){
    float a0=A[3*i], a1=A[3*i+1], a2=A[3*i+2];
    #pragma unroll
    for (int l=0;l<3;l++)
      C[3*i+l] = a0*B[l] + a1*B[3+l] + a2*B[6+l];
  }
}

// ============================== MAIN PATH ==================================
// prep: blocks 0,1 = H tables (u-order + conj-reflected H2); blocks 2..129 = scan
__global__ __launch_bounds__(NTHR) void prep(
  const float* __restrict__ x, const float* __restrict__ A1, const float* __restrict__ A2,
  const float* fW1, const float* fb1p, const float* fW2, const float* fb2p,
  const float* fpW1, const float* fpb1, const float* fpW2, const float* fpb2,
  const float* gW1, const float* gb1, const float* gW2, const float* gb2,
  const float* gpW1, const float* gpb1, const float* gpW2, const float* gpb2,
  float* __restrict__ X, float2* __restrict__ Hcf, float2* __restrict__ Hcf2,
  float2* __restrict__ Hcg, float2* __restrict__ Hcg2)
{
  __shared__ float2 buf[BUFSZ];
  int tid = threadIdx.x;
  if (blockIdx.x < 2){
    const float *aW1,*ab1,*aW2,*ab2,*bW1,*bb1,*bW2,*bb2; float2 *outp, *outp2; int revd;
    if (blockIdx.x == 0){ aW1=fW1; ab1=fb1p; aW2=fW2; ab2=fb2p;
      bW1=fpW1; bb1=fpb1; bW2=fpW2; bb2=fpb2; outp=Hcf; outp2=Hcf2; revd=1; }
    else { aW1=gW1; ab1=gb1; aW2=gW2; ab2=gb2;
      bW1=gpW1; bb1=gpb1; bW2=gpW2; bb2=gpb2; outp=Hcg; outp2=Hcg2; revd=0; }
    float w1a[5],b1a[5],w2a[5],w1b[5],b1b[5],w2b[5];
    #pragma unroll
    for (int h=0;h<5;h++){
      w1a[h]=aW1[h]; b1a[h]=ab1[h]; w2a[h]=aW2[h];
      w1b[h]=bW1[h]; b1b[h]=bb1[h]; w2b[h]=bW2[h];
    }
    float cA = ab2[0], cB = bb2[0];
    const float nis = -3.14159265358979f / 4096.f;
    #pragma unroll
    for (int r = 0; r < 2048/NTHR; ++r){
      int j = tid + NTHR*r;
      float2 zz[2];
      #pragma unroll
      for (int h2 = 0; h2 < 2; ++h2){
        int n = j + 2048*h2;
        float t = revd ? (float)(TT-1-n) : (float)n;
        float va = cA, vb = cB;
        #pragma unroll
        for (int h=0;h<5;h++){
          va += w2a[h]*tanhf(w1a[h]*t + b1a[h]);
          vb += w2b[h]*tanhf(w1b[h]*t + b1b[h]);
        }
        zz[h2] = make_float2(va, vb);
      }
      float sn, cs; __sincosf(nis*(float)j, &sn, &cs);
      float2 wA = make_float2(cs, sn);
      float2 wB = make_float2(cs*cs - sn*sn, 2.f*cs*sn);
      float2 w3 = cmulf(wA, wB);
      float2 a = zz[0], b = zz[1];
      BREF(buf,j)      = cadd(a,b);
      BREF(buf,j+2048) = cmulf(csub(a,b), wB);
      BREF(buf,j+4096) = cmulf(wA, make_float2(a.x + b.y, a.y - b.x));
      BREF(buf,j+6144) = cmulf(w3, make_float2(a.x - b.y, a.y + b.x));
    }
    __syncthreads(); fwd_pass<512>(buf, tid);
    __syncthreads(); fwd_pass<128>(buf, tid);
    __syncthreads(); fwd_pass<32>(buf, tid);
    __syncthreads(); fwd_pass<8>(buf, tid);
    __syncthreads(); fwd_final8(buf, tid);
    __syncthreads();
    #pragma unroll
    for (int r=0;r<NFFT/NTHR;r++){
      int p = tid + NTHR*r;
      outp[p] = BREF(buf,p);
      int k  = (int)(__brev((unsigned)p) >> (32-LOGN));
      int kk = (NFFT - k) & (NFFT-1);
      int q  = (int)(__brev((unsigned)kk) >> (32-LOGN));
      float2 z = BREF(buf,q);
      outp2[p] = make_float2(z.x, -z.y);
    }
  } else {
    float* sc = (float*)buf;
    int b = blockIdx.x - 2, j = tid;
    float k1x = A1[7]-A1[5], k1y = A1[2]-A1[6], k1z = A1[3]-A1[1];
    float k2x = A2[7]-A2[5], k2y = A2[2]-A2[6], k2z = A2[3]-A2[1];
    float L[9] = {1,0,0, 0,1,0, 0,0,1};
    #pragma unroll 1
    for (int k=1;k<=8;k++){
      int t = 8*j + k;
      if (t < TT){
        float z0 = x[((size_t)b*TT + t)*2 + 0];
        float z1 = x[((size_t)b*TT + t)*2 + 1];
        float R[9];
        rot3(k1x*z0 + k2x*z1, k1y*z0 + k2y*z1, k1z*z0 + k2z*z1, R);
        float Cm[9]; mm3(L, R, Cm);
        #pragma unroll
        for (int m=0;m<9;m++) L[m] = Cm[m];
      }
    }
    #pragma unroll
    for (int m=0;m<9;m++) sc[(0*512 + j)*9 + m] = L[m];
    int cur = 0;
    for (int d=1; d<512; d<<=1){
      __syncthreads();
      float own[9], res[9];
      #pragma unroll
      for (int m=0;m<9;m++) own[m] = sc[(cur*512 + j)*9 + m];
      if (j >= d){
        float prev[9];
        #pragma unroll
        for (int m=0;m<9;m++) prev[m] = sc[(cur*512 + j - d)*9 + m];
        mm3(prev, own, res);
      } else {
        #pragma unroll
        for (int m=0;m<9;m++) res[m] = own[m];
      }
      #pragma unroll
      for (int m=0;m<9;m++) sc[((cur^1)*512 + j)*9 + m] = res[m];
      cur ^= 1;
    }
    __syncthreads();
    float Xc[9];
    if (j == 0){
      Xc[0]=1;Xc[1]=0;Xc[2]=0;Xc[3]=0;Xc[4]=1;Xc[5]=0;Xc[6]=0;Xc[7]=0;Xc[8]=1;
    } else {
      #pragma unroll
      for (int m=0;m<9;m++) Xc[m] = sc[(cur*512 + j - 1)*9 + m];
    }
    #pragma unroll
    for (int m=0;m<9;m++) X[((size_t)b*9 + m)*TT + 8*j] = Xc[m];
    #pragma unroll 1
    for (int k=1;k<8;k++){
      int t = 8*j + k;
      float z0 = x[((size_t)b*TT + t)*2 + 0];
      float z1 = x[((size_t)b*TT + t)*2 + 1];
      float R[9];
      rot3(k1x*z0 + k2x*z1, k1y*z0 + k2y*z1, k1z*z0 + k2z*z1, R);
      float Cm[9]; mm3(Xc, R, Cm);
      #pragma unroll
      for (int m=0;m<9;m++){ Xc[m] = Cm[m]; X[((size_t)b*9 + m)*TT + t] = Xc[m]; }
    }
  }
}

// convk5: register-blocked radix-16 FFT. 3 barriers/fwd, 4/inv; linear 64 KB
// LDS with XOR swizzle; Z in registers; launch_bounds(512,2) -> VGPR cap 128.
__global__ __launch_bounds__(NTHR, 2) void convk5(const float* __restrict__ X,
    const float2* __restrict__ Hcf, const float2* __restrict__ Hcf2,
    const float2* __restrict__ Hcg, const float2* __restrict__ Hcg2,
    float* __restrict__ tmp)
{
  __shared__ float2 buf[NFFT];
  int tid = threadIdx.x;
  int task = blockIdx.x;
  int b1i, c1, b2i, c2; bool cross;
  if (task < 384){
    int b = task/3, p = task % 3;
    b1i = b; b2i = b; cross = true;
    c1 = (p==0)?1:((p==1)?2:5);
    c2 = (p==0)?3:((p==1)?6:7);
  } else if (task < 512){
    int b = task - 384; b1i=b; b2i=b; c1=0; c2=4; cross=false;
  } else {
    int q = task - 512; b1i = 2*q; b2i = 2*q+1; c1=8; c2=8; cross=false;
  }
  const float* x1 = X + ((size_t)b1i*9 + c1)*TT;
  const float* x2 = X + ((size_t)b2i*9 + c2)*TT;

  // ---- forward P1: sigma=512, c=tid, zero-pad-aware radix-16
  {
    float2 v[16];
    DEF_C8;
    #pragma unroll
    for (int t=0;t<8;t++){
      int n = tid + 512*t;
      v[t] = make_float2(x1[n], x2[n]);
    }
    float sn, cs; __sincosf(-3.14159265358979f*(float)tid/4096.f, &sn, &cs);
    float2 u1 = make_float2(cs, sn);
    #pragma unroll
    for (int t=0;t<8;t++) v[t+8] = cmulf(v[t], cmulf(u1, C8[t]));   // b==0 stage
    rad16_fwd_tail(v, csq(u1));
    #pragma unroll
    for (int t=0;t<16;t++) buf[SWZ(tid + 512*t)] = v[t];
  }
  __syncthreads();
  // ---- forward P2: sigma=32
  {
    float2 v[16];
    int base = 512*(tid>>5), c = tid&31;
    #pragma unroll
    for (int t=0;t<16;t++) v[t] = buf[SWZ(base + c + 32*t)];
    float sn, cs; __sincosf(-3.14159265358979f*(float)c/256.f, &sn, &cs);
    rad16_fwd(v, make_float2(cs, sn));
    #pragma unroll
    for (int t=0;t<16;t++) buf[SWZ(base + c + 32*t)] = v[t];
  }
  __syncthreads();
  // ---- forward P3: sigma=2
  {
    float2 v[16];
    int base = 32*(tid>>1), c = tid&1;
    #pragma unroll
    for (int t=0;t<16;t++) v[t] = buf[SWZ(base + c + 2*t)];
    float2 u1 = c ? make_float2(0.9807852804f, -0.1950903220f) : make_float2(1.f, 0.f);
    rad16_fwd(v, u1);
    #pragma unroll
    for (int t=0;t<16;t++) buf[SWZ(base + c + 2*t)] = v[t];
  }
  __syncthreads();
  // ---- forward P4: own contiguous-16 + final s=1 stage -> zreg (no barrier after)
  float2 zreg[16];
  {
    #pragma unroll
    for (int j=0;j<16;j++) zreg[j] = buf[SWZ(16*tid + j)];
    #pragma unroll
    for (int g=0; g<16; g+=2){
      float2 a = zreg[g], b = zreg[g+1];
      zreg[g] = cadd(a,b); zreg[g+1] = csub(a,b);
    }
  }

  // W1 = N*[(x1*f - x2*fp) + i(x1*fp + x2*f)] ; W2 = N*[(x1*f + x2*fp) + i(x2*f - x1*fp)]
  float2 w1y[8], w2y[8];
  inv16<true >(buf, tid, zreg, Hcf,  w1y);
  inv16<false>(buf, tid, zreg, Hcf2, w2y);
  float a1[8], a2[8], bb1[8], bb2[8];   // N*(x1*f), N*(x2*f), N*(x1*fp), N*(x2*fp)
  #pragma unroll
  for (int e = 0; e < 8; ++e){
    a1[e]  = 0.5f*(w1y[e].x + w2y[e].x);
    a2[e]  = 0.5f*(w1y[e].y + w2y[e].y);
    bb1[e] = 0.5f*(w1y[e].y - w2y[e].y);
    bb2[e] = 0.5f*(w2y[e].x - w1y[e].x);
  }
  float2 v1y[8], v2y[8];
  inv16<false>(buf, tid, zreg, Hcg,  v1y);
  inv16<false>(buf, tid, zreg, Hcg2, v2y);

  const float invN2 = (1.0f/NFFT)*(1.0f/NFFT);
  float* op1 = tmp + ((size_t)b1i*9 + c1)*TT;
  float* op2 = tmp + ((size_t)b2i*9 + c2)*TT;
  #pragma unroll
  for (int e = 0; e < 8; ++e){
    int s = tid + 512*e;
    float c1v = 0.5f*(v1y[e].x + v2y[e].x);   // N*(x1*g)
    float c2v = 0.5f*(v1y[e].y + v2y[e].y);   // N*(x2*g)
    float d1  = 0.5f*(v1y[e].y - v2y[e].y);   // N*(x1*gp)
    float d2  = 0.5f*(v2y[e].x - v1y[e].x);   // N*(x2*gp)
    float Af1 = cross ? a2[e]  : a1[e];
    float Bf1 = cross ? bb2[e] : bb1[e];
    float Af2 = cross ? a1[e]  : a2[e];
    float Bf2 = cross ? bb1[e] : bb2[e];
    op1[s] = (Af1*c1v + Bf1*d1) * invN2;
    op2[s] = (Af2*c2v + Bf2*d2) * invN2;
  }
}

// repack: (b,9,T) channel-major -> (b,T,9) interleaved, LDS-tiled
__global__ __launch_bounds__(256) void repack(const float* __restrict__ tmp,
                                              float* __restrict__ out){
  __shared__ float tile[9][264];
  int b  = blockIdx.x >> 4;
  int t0 = (blockIdx.x & 15) << 8;
  int tid = threadIdx.x;
  #pragma unroll
  for (int c = 0; c < 9; ++c)
    tile[c][tid] = tmp[((size_t)b*9 + c)*TT + t0 + tid];
  __syncthreads();
  size_t base = ((size_t)b*TT + t0)*9;
  #pragma unroll
  for (int k = 0; k < 9; ++k){
    int idx = tid + 256*k;
    out[base + idx] = tile[idx % 9][idx / 9];
  }
}

// ============================ FALLBACK (R1) ================================
__device__ void fft_dif_bitrev(float2* buf, int tid){
  const float PI = 3.14159265358979f;
  #pragma unroll 1
  for (int stage = 0; stage < LOGN; ++stage){
    int logspan = LOGN - 1 - stage;
    int span = 1 << logspan;
    float nis = -PI / (float)span;
    __syncthreads();
    #pragma unroll
    for (int r = 0; r < NFFT/2/NTHR; ++r){
      int j = tid + NTHR*r;
      int off = j & (span - 1);
      int i0 = ((j >> logspan) << (logspan + 1)) + off;
      int i1 = i0 + span;
      float2 a = buf[i0], b = buf[i1];
      float ang = nis * (float)off;
      float sn, cs;
      __sincosf(ang, &sn, &cs);
      float2 d = make_float2(a.x - b.x, a.y - b.y);
      buf[i0] = make_float2(a.x + b.x, a.y + b.y);
      buf[i1] = cmulf(d, make_float2(cs, sn));
    }
  }
  __syncthreads();
  #pragma unroll
  for (int r = 0; r < NFFT/NTHR; ++r){
    int p = tid + NTHR*r;
    int q = (int)(__brev((unsigned)p) >> (32 - LOGN));
    if (p < q){ float2 t = buf[p]; buf[p] = buf[q]; buf[q] = t; }
  }
  __syncthreads();
}

__global__ __launch_bounds__(NTHR) void hker_fb(
  const float* fW1, const float* fb1p, const float* fW2, const float* fb2p,
  const float* fpW1, const float* fpb1, const float* fpW2, const float* fpb2,
  const float* gW1, const float* gb1, const float* gW2, const float* gb2,
  const float* gpW1, const float* gpb1, const float* gpW2, const float* gpb2,
  float2* Hcf, float2* Hcg)
{
  __shared__ float2 buf[NFFT];
  int tid = threadIdx.x;
  const float *aW1,*ab1,*aW2,*ab2,*bW1,*bb1,*bW2,*bb2; float2* outp; int revd;
  if (blockIdx.x == 0){ aW1=fW1; ab1=fb1p; aW2=fW2; ab2=fb2p;
    bW1=fpW1; bb1=fpb1; bW2=fpW2; bb2=fpb2; outp=Hcf; revd=1; }
  else { aW1=gW1; ab1=gb1; aW2=gW2; ab2=gb2;
    bW1=gpW1; bb1=gpb1; bW2=gpW2; bb2=gpb2; outp=Hcg; revd=0; }
  float w1a[5],b1a[5],w2a[5],w1b[5],b1b[5],w2b[5];
  #pragma unroll
  for (int h=0;h<5;h++){
    w1a[h]=aW1[h]; b1a[h]=ab1[h]; w2a[h]=aW2[h];
    w1b[h]=bW1[h]; b1b[h]=bb1[h]; w2b[h]=bW2[h];
  }
  float cA = ab2[0], cB = bb2[0];
  for (int r=0;r<NFFT/NTHR;r++){
    int s = tid + NTHR*r;
    float2 v = make_float2(0.f, 0.f);
    if (s < TT){
      float t = revd ? (float)(TT-1-s) : (float)s;
      float va = cA, vb = cB;
      #pragma unroll
      for (int h=0;h<5;h++){
        va += w2a[h]*tanhf(w1a[h]*t + b1a[h]);
        vb += w2b[h]*tanhf(w1b[h]*t + b1b[h]);
      }
      v = make_float2(va, vb);
    }
    buf[s] = v;
  }
  fft_dif_bitrev(buf, tid);
  for (int r=0;r<NFFT/NTHR;r++){ int k = tid + NTHR*r; outp[k] = buf[k]; }
}

__global__ __launch_bounds__(256) void scank_fb(const float* __restrict__ x,
    const float* __restrict__ A1, const float* __restrict__ A2,
    float* __restrict__ X)
{
  __shared__ float sc[2][256][9];
  int b = blockIdx.x, j = threadIdx.x;
  float k1x = A1[7]-A1[5], k1y = A1[2]-A1[6], k1z = A1[3]-A1[1];
  float k2x = A2[7]-A2[5], k2y = A2[2]-A2[6], k2z = A2[3]-A2[1];
  float L[9] = {1,0,0, 0,1,0, 0,0,1};
  #pragma unroll 1
  for (int k=1;k<=16;k++){
    int t = 16*j + k;
    if (t < TT){
      float z0 = x[((size_t)b*TT + t)*2 + 0];
      float z1 = x[((size_t)b*TT + t)*2 + 1];
      float R[9];
      rot3(k1x*z0 + k2x*z1, k1y*z0 + k2y*z1, k1z*z0 + k2z*z1, R);
      float Cm[9]; mm3(L, R, Cm);
      #pragma unroll
      for (int m=0;m<9;m++) L[m] = Cm[m];
    }
  }
  #pragma unroll
  for (int m=0;m<9;m++) sc[0][j][m] = L[m];
  int cur = 0;
  for (int d=1; d<256; d<<=1){
    __syncthreads();
    float own[9], res[9];
    #pragma unroll
    for (int m=0;m<9;m++) own[m] = sc[cur][j][m];
    if (j >= d){
      float prev[9];
      #pragma unroll
      for (int m=0;m<9;m++) prev[m] = sc[cur][j-d][m];
      mm3(prev, own, res);
    } else {
      #pragma unroll
      for (int m=0;m<9;m++) res[m] = own[m];
    }
    #pragma unroll
    for (int m=0;m<9;m++) sc[cur^1][j][m] = res[m];
    cur ^= 1;
  }
  __syncthreads();
  float Xc[9];
  if (j == 0){
    Xc[0]=1;Xc[1]=0;Xc[2]=0;Xc[3]=0;Xc[4]=1;Xc[5]=0;Xc[6]=0;Xc[7]=0;Xc[8]=1;
  } else {
    #pragma unroll
    for (int m=0;m<9;m++) Xc[m] = sc[cur][j-1][m];
  }
  #pragma unroll
  for (int m=0;m<9;m++) X[((size_t)b*9 + m)*TT + 16*j] = Xc[m];
  #pragma unroll 1
  for (int k=1;k<16;k++){
    int t = 16*j + k;
    float z0 = x[((size_t)b*TT + t)*2 + 0];
    float z1 = x[((size_t)b*TT + t)*2 + 1];
    float R[9];
    rot3(k1x*z0 + k2x*z1, k1y*z0 + k2y*z1, k1z*z0 + k2z*z1, R);
    float Cm[9]; mm3(Xc, R, Cm);
    #pragma unroll
    for (int m=0;m<9;m++){ Xc[m] = Cm[m]; X[((size_t)b*9 + m)*TT + t] = Xc[m]; }
  }
}

__global__ __launch_bounds__(NTHR) void convk_fb(const float* __restrict__ X,
    const float2* __restrict__ Hcf, const float2* __restrict__ Hcg,
    float* __restrict__ out)
{
  __shared__ float2 buf[NFFT];
  __shared__ float2 fb1[NFFT/2 + 2];
  __shared__ float2 fb2[NFFT/2 + 2];
  int tid = threadIdx.x;
  int task = blockIdx.x;
  int b1i, c1, b2i, c2; bool cross;
  if (task < 384){
    int b = task/3, p = task % 3;
    b1i = b; b2i = b; cross = true;
    c1 = (p==0)?1:((p==1)?2:5);
    c2 = (p==0)?3:((p==1)?6:7);
  } else if (task < 512){
    int b = task - 384; b1i=b; b2i=b; c1=0; c2=4; cross=false;
  } else {
    int q = task - 512; b1i = 2*q; b2i = 2*q+1; c1=8; c2=8; cross=false;
  }
  const float* x1 = X + ((size_t)b1i*9 + c1)*TT;
  const float* x2 = X + ((size_t)b2i*9 + c2)*TT;
  #pragma unroll
  for (int r=0;r<NFFT/NTHR;r++){
    int s = tid + NTHR*r;
    float2 v = make_float2(0.f,0.f);
    if (s < TT){ v.x = x1[s]; v.y = x2[s]; }
    buf[s] = v;
  }
  fft_dif_bitrev(buf, tid);
  for (int k = tid; k <= NFFT/2; k += NTHR){
    int kk = (NFFT - k) & (NFFT - 1);
    float2 zk = buf[k], zn = buf[kk];
    fb1[k] = make_float2(0.5f*(zk.x + zn.x), 0.5f*(zk.y - zn.y));
    fb2[k] = make_float2(0.5f*(zk.y + zn.y), 0.5f*(zn.x - zk.x));
  }
  __syncthreads();
  const float invN2 = (1.0f/NFFT)*(1.0f/NFFT);
  #pragma unroll 1
  for (int pass = 0; pass < 2; ++pass){
    const float2* fA = (pass==0) ? (cross ? fb2 : fb1) : (cross ? fb1 : fb2);
    const float2* fG = (pass==0) ? fb1 : fb2;
    int ob = (pass==0) ? b1i : b2i;
    int oc = (pass==0) ? c1 : c2;
    #pragma unroll
    for (int r=0;r<NFFT/NTHR;r++){
      int k = tid + NTHR*r;
      float2 F;
      if (k <= NFFT/2) F = fA[k];
      else { float2 g = fA[NFFT-k]; F = make_float2(g.x, -g.y); }
      float2 P = cmulf(F, Hcf[k]);
      buf[k] = make_float2(P.x, -P.y);
    }
    fft_dif_bitrev(buf, tid);
    float rA[8], rB[8];
    #pragma unroll
    for (int r=0;r<8;r++){
      int s = tid + NTHR*r;
      rA[r] = buf[s].x;
      rB[r] = -buf[s].y;
    }
    #pragma unroll
    for (int r=0;r<NFFT/NTHR;r++){
      int k = tid + NTHR*r;
      float2 F;
      if (k <= NFFT/2) F = fG[k];
      else { float2 g = fG[NFFT-k]; F = make_float2(g.x, -g.y); }
      float2 P = cmulf(F, Hcg[k]);
      buf[k] = make_float2(P.x, -P.y);
    }
    fft_dif_bitrev(buf, tid);
    #pragma unroll
    for (int r=0;r<8;r++){
      int s = tid + NTHR*r;
      float AB = buf[s].x, BB = -buf[s].y;
      out[((size_t)ob*TT + s)*9 + oc] = (rA[r]*AB + rB[r]*BB) * invN2;
    }
  }
}

// ================================ HOST =====================================
extern "C" void kernel_launch(void* const* d_in, const int* in_sizes, int n_in,
                              void* d_out, int out_size, void* d_ws, size_t ws_size,
                              hipStream_t stream){
  const float* x  = (const float*)d_in[0];
  const float* A1 = (const float*)d_in[1];
  const float* A2 = (const float*)d_in[2];
  const float* P[16];
  for (int i=0;i<16;i++) P[i] = (const float*)d_in[3+i];

  size_t xbytes = (size_t)BS*9*TT*sizeof(float);               // 18,874,368
  size_t hbytes = (size_t)NFFT*sizeof(float2);                 // 65,536
  float*  Xb   = (float*)d_ws;
  float2* Hcf  = (float2*)((char*)d_ws + xbytes);
  float2* Hcf2 = Hcf + NFFT;
  float2* Hcg  = Hcf + 2*NFFT;
  float2* Hcg2 = Hcf + 3*NFFT;
  float*  tmp  = (float*)((char*)d_ws + xbytes + 4*hbytes);
  size_t need = xbytes + 4*hbytes + xbytes;

  if (ws_size >= need){
    prep<<<2 + BS, NTHR, 0, stream>>>(x, A1, A2,
        P[0],P[1],P[2],P[3],P[4],P[5],P[6],P[7],
        P[8],P[9],P[10],P[11],P[12],P[13],P[14],P[15],
        Xb, Hcf, Hcf2, Hcg, Hcg2);
    convk5<<<NTASK, NTHR, 0, stream>>>(Xb, Hcf, Hcf2, Hcg, Hcg2, tmp);
    repack<<<BS*16, 256, 0, stream>>>(tmp, (float*)d_out);
  } else {
    hker_fb<<<2, NTHR, 0, stream>>>(P[0],P[1],P[2],P[3],P[4],P[5],P[6],P[7],
        P[8],P[9],P[10],P[11],P[12],P[13],P[14],P[15], Hcf, Hcg);
    scank_fb<<<BS, 256, 0, stream>>>(x, A1, A2, Xb);
    convk_fb<<<NTASK, NTHR, 0, stream>>>(Xb, Hcf, Hcg, (float*)d_out);
  }
}

// Round 11
// 215.477 us; speedup vs baseline: 1.2693x; 1.2693x over previous
//
#include <hip/hip_runtime.h>
#include <math.h>

#define TT    4096
#define NFFT  8192
#define LOGN  13
#define NTHR  512
#define BS    128
#define NTASK 576
#define BUFSZ (NFFT + NFFT/8)   // prep/fallback buffer (additive swizzle)

__device__ __forceinline__ float2 cmulf(float2 u, float2 v){
  return make_float2(u.x*v.x - u.y*v.y, u.x*v.y + u.y*v.x);
}
__device__ __forceinline__ float2 cadd(float2 a, float2 b){ return make_float2(a.x+b.x, a.y+b.y); }
__device__ __forceinline__ float2 csub(float2 a, float2 b){ return make_float2(a.x-b.x, a.y-b.y); }
__device__ __forceinline__ float2 cmuli (float2 a){ return make_float2(-a.y,  a.x); }
__device__ __forceinline__ float2 cmulni(float2 a){ return make_float2( a.y, -a.x); }
__device__ __forceinline__ float2 csq(float2 a){ return make_float2(a.x*a.x - a.y*a.y, 2.f*a.x*a.y); }

// prep/fallback LDS accessor (additive swizzle)
__device__ __forceinline__ float2& BREF(float2* b, int i){ return b[i + (i>>3)]; }
// convk6 LDS swizzle (proven 12x conflict cut in R8): XOR fold bits 4-7 into 0-3
#define SWZ(p) ((p) ^ (((p)>>4)&15))

constexpr int ctz_c(int v){ int c=0; while(!(v&1)){ v>>=1; c++; } return c; }

// ==================== convk6 pass helpers (SWZ, linear buf) ================
template<int S>
__device__ __forceinline__ void fwd_passS(float2* buf, int tid){
  constexpr int LS = ctz_c(S);
  const float nis = -3.14159265358979f / (2.0f * (float)S);
  #pragma unroll
  for (int r = 0; r < (NFFT/4)/NTHR; ++r){
    int j   = tid + NTHR*r;
    int off = j & (S-1);
    int i0  = ((j >> LS) << (LS+2)) + off;
    float2 a = buf[SWZ(i0)], b = buf[SWZ(i0+S)], c = buf[SWZ(i0+2*S)], d = buf[SWZ(i0+3*S)];
    float sn, cs; __sincosf(nis*(float)off, &sn, &cs);
    float2 wA = make_float2(cs, sn);
    float2 wB = make_float2(cs*cs - sn*sn, 2.f*cs*sn);
    float2 w3 = cmulf(wA, wB);
    float2 s02 = cadd(a,c), d02 = csub(a,c);
    float2 s13 = cadd(b,d), d13 = csub(b,d);
    buf[SWZ(i0)]     = cadd(s02, s13);
    buf[SWZ(i0+S)]   = cmulf(csub(s02, s13), wB);
    buf[SWZ(i0+2*S)] = cmulf(wA, cadd(d02, cmulni(d13)));
    buf[SWZ(i0+3*S)] = cmulf(w3, cadd(d02, cmuli (d13)));
  }
}

template<int S>
__device__ __forceinline__ void inv_passS(float2* buf, int tid){
  constexpr int LS = ctz_c(S);
  const float pis = 3.14159265358979f / (2.0f * (float)S);
  #pragma unroll
  for (int r = 0; r < (NFFT/4)/NTHR; ++r){
    int j   = tid + NTHR*r;
    int off = j & (S-1);
    int i0  = ((j >> LS) << (LS+2)) + off;
    float2 a = buf[SWZ(i0)], b = buf[SWZ(i0+S)], c = buf[SWZ(i0+2*S)], d = buf[SWZ(i0+3*S)];
    float sn, cs; __sincosf(pis*(float)off, &sn, &cs);
    float2 u  = make_float2(cs, sn);
    float2 u2 = make_float2(cs*cs - sn*sn, 2.f*cs*sn);
    float2 u2b = cmulf(u2, b), u2d = cmulf(u2, d);
    float2 t0 = cadd(a,u2b), t1 = csub(a,u2b);
    float2 t2 = cadd(c,u2d), t3 = csub(c,u2d);
    float2 ut2  = cmulf(u, t2);
    float2 iut3 = cmuli(cmulf(u, t3));
    buf[SWZ(i0)]     = cadd(t0, ut2);
    buf[SWZ(i0+2*S)] = csub(t0, ut2);
    buf[SWZ(i0+S)]   = cadd(t1, iut3);
    buf[SWZ(i0+3*S)] = csub(t1, iut3);
  }
}

// Forward final pass ending in REGISTERS (zreg[16], fill-pattern order 8m+l).
__device__ __forceinline__ void fwd_final8_regS(float2* buf, int tid, float2* zreg){
  const float R2 = 0.70710678118654752f;
  #pragma unroll
  for (int rr = 0; rr < 2; ++rr){
    int m = tid + NTHR*rr;
    float2 v[8];
    #pragma unroll
    for (int l=0;l<8;l++) v[l] = buf[SWZ(8*m+l)];
    { float2 t = csub(v[0], v[4]); v[0] = cadd(v[0], v[4]); v[4] = t; }
    { float2 t = csub(v[1], v[5]); v[1] = cadd(v[1], v[5]); v[5] = cmulf(t, make_float2(R2, -R2)); }
    { float2 t = csub(v[2], v[6]); v[2] = cadd(v[2], v[6]); v[6] = cmulni(t); }
    { float2 t = csub(v[3], v[7]); v[3] = cadd(v[3], v[7]); v[7] = cmulf(t, make_float2(-R2, -R2)); }
    #pragma unroll
    for (int base = 0; base < 8; base += 4){
      { float2 t = csub(v[base],   v[base+2]); v[base]   = cadd(v[base],   v[base+2]); v[base+2] = t; }
      { float2 t = csub(v[base+1], v[base+3]); v[base+1] = cadd(v[base+1], v[base+3]); v[base+3] = cmulni(t); }
    }
    #pragma unroll
    for (int p = 0; p < 8; p += 2){ float2 t = csub(v[p], v[p+1]); v[p] = cadd(v[p], v[p+1]); v[p+1] = t; }
    #pragma unroll
    for (int l=0;l<8;l++) zreg[rr*8+l] = v[l];
  }
}

// Inverse transform of (Z .* H), Z in registers (fill-pattern order), H global
// u-order. Output: yout[2r] = pos tid+512r, yout[2r+1] = pos +2048 (r<4).
// Fill writes the thread's OWN positions -> caller barriers before if needed.
__device__ __forceinline__ void inv_zhS(float2* buf, int tid,
                                        const float2* zreg,
                                        const float2* __restrict__ H,
                                        float2* yout){
  const float R2 = 0.70710678118654752f;
  #pragma unroll
  for (int rr = 0; rr < 2; ++rr){
    int m = tid + NTHR*rr;
    float2 v[8];
    #pragma unroll
    for (int l = 0; l < 8; ++l) v[l] = cmulf(zreg[rr*8+l], H[8*m+l]);
    // span1 DIT (w=1)
    #pragma unroll
    for (int p = 0; p < 8; p += 2){ float2 t = v[p+1]; v[p+1] = csub(v[p], t); v[p] = cadd(v[p], t); }
    // span2 DIT: pre-twiddle w = {1, +i}
    #pragma unroll
    for (int base = 0; base < 8; base += 4){
      { float2 t = v[base+2];        v[base+2] = csub(v[base],   t); v[base]   = cadd(v[base],   t); }
      { float2 t = cmuli(v[base+3]); v[base+3] = csub(v[base+1], t); v[base+1] = cadd(v[base+1], t); }
    }
    // span4 DIT: pre-twiddle w = exp(+i pi l/4)
    { float2 t = v[4];                              v[4] = csub(v[0], t); v[0] = cadd(v[0], t); }
    { float2 t = cmulf(v[5], make_float2(R2, R2));  v[5] = csub(v[1], t); v[1] = cadd(v[1], t); }
    { float2 t = cmuli(v[6]);                       v[6] = csub(v[2], t); v[2] = cadd(v[2], t); }
    { float2 t = cmulf(v[7], make_float2(-R2, R2)); v[7] = csub(v[3], t); v[3] = cadd(v[3], t); }
    #pragma unroll
    for (int l = 0; l < 8; ++l) buf[SWZ(8*m+l)] = v[l];
  }
  __syncthreads();
  inv_passS<8>(buf, tid);   __syncthreads();
  inv_passS<32>(buf, tid);  __syncthreads();
  inv_passS<128>(buf, tid); __syncthreads();
  inv_passS<512>(buf, tid); __syncthreads();
  // final spans (2048,4096): only outputs 0..4095 needed -> registers
  const float pis = 3.14159265358979f / 4096.f;
  #pragma unroll
  for (int r = 0; r < 4; ++r){
    int j = tid + NTHR*r;
    float sn, cs; __sincosf(pis*(float)j, &sn, &cs);
    float2 u  = make_float2(cs, sn);
    float2 u2 = make_float2(cs*cs - sn*sn, 2.f*cs*sn);
    float2 a = buf[SWZ(j)], b = buf[SWZ(j+2048)], c = buf[SWZ(j+4096)], d = buf[SWZ(j+6144)];
    float2 u2b = cmulf(u2, b), u2d = cmulf(u2, d);
    float2 t0 = cadd(a, u2b), t1 = csub(a, u2b);
    float2 t2 = cadd(c, u2d), t3 = csub(c, u2d);
    yout[2*r]   = cadd(t0, cmulf(u, t2));
    yout[2*r+1] = cadd(t1, cmuli(cmulf(u, t3)));
  }
}

// ==================== prep pass helpers (BREF, padded buf) =================
template<int S>
__device__ __forceinline__ void fwd_pass(float2* buf, int tid){
  constexpr int LS = ctz_c(S);
  const float nis = -3.14159265358979f / (2.0f * (float)S);
  #pragma unroll
  for (int r = 0; r < (NFFT/4)/NTHR; ++r){
    int j   = tid + NTHR*r;
    int off = j & (S-1);
    int i0  = ((j >> LS) << (LS+2)) + off;
    float2 a = BREF(buf,i0), b = BREF(buf,i0+S), c = BREF(buf,i0+2*S), d = BREF(buf,i0+3*S);
    float sn, cs; __sincosf(nis*(float)off, &sn, &cs);
    float2 wA = make_float2(cs, sn);
    float2 wB = make_float2(cs*cs - sn*sn, 2.f*cs*sn);
    float2 w3 = cmulf(wA, wB);
    float2 s02 = cadd(a,c), d02 = csub(a,c);
    float2 s13 = cadd(b,d), d13 = csub(b,d);
    BREF(buf,i0)     = cadd(s02, s13);
    BREF(buf,i0+S)   = cmulf(csub(s02, s13), wB);
    BREF(buf,i0+2*S) = cmulf(wA, cadd(d02, cmulni(d13)));
    BREF(buf,i0+3*S) = cmulf(w3, cadd(d02, cmuli (d13)));
  }
}

__device__ __forceinline__ void fwd_final8(float2* buf, int tid){
  const float R2 = 0.70710678118654752f;
  #pragma unroll
  for (int r = 0; r < (NFFT/8)/NTHR; ++r){
    int m = tid + NTHR*r;
    float2 v[8];
    #pragma unroll
    for (int l=0;l<8;l++) v[l] = BREF(buf,8*m+l);
    { float2 t = csub(v[0], v[4]); v[0] = cadd(v[0], v[4]); v[4] = t; }
    { float2 t = csub(v[1], v[5]); v[1] = cadd(v[1], v[5]); v[5] = cmulf(t, make_float2(R2, -R2)); }
    { float2 t = csub(v[2], v[6]); v[2] = cadd(v[2], v[6]); v[6] = cmulni(t); }
    { float2 t = csub(v[3], v[7]); v[3] = cadd(v[3], v[7]); v[7] = cmulf(t, make_float2(-R2, -R2)); }
    #pragma unroll
    for (int base = 0; base < 8; base += 4){
      { float2 t = csub(v[base],   v[base+2]); v[base]   = cadd(v[base],   v[base+2]); v[base+2] = t; }
      { float2 t = csub(v[base+1], v[base+3]); v[base+1] = cadd(v[base+1], v[base+3]); v[base+3] = cmulni(t); }
    }
    #pragma unroll
    for (int p = 0; p < 8; p += 2){ float2 t = csub(v[p], v[p+1]); v[p] = cadd(v[p], v[p+1]); v[p+1] = t; }
    #pragma unroll
    for (int l=0;l<8;l++) BREF(buf,8*m+l) = v[l];
  }
}

// ---------------- Rodrigues rotation from skew axis
__device__ __forceinline__ void rot3(float ax, float ay, float az, float* R){
  float th2 = ax*ax + ay*ay + az*az;
  float s1, s2;
  if (th2 < 1e-8f){
    s1 = 1.f - th2*(1.f/6.f);
    s2 = 0.5f - th2*(1.f/24.f);
  } else {
    float th = sqrtf(th2);
    float sn = sinf(th);
    s1 = sn / th;
    float sh = sinf(0.5f*th);
    s2 = 2.f*sh*sh / th2;
  }
  R[0] = 1.f - s2*(ay*ay+az*az);
  R[1] = -s1*az + s2*ax*ay;
  R[2] =  s1*ay + s2*ax*az;
  R[3] =  s1*az + s2*ax*ay;
  R[4] = 1.f - s2*(ax*ax+az*az);
  R[5] = -s1*ax + s2*ay*az;
  R[6] = -s1*ay + s2*ax*az;
  R[7] =  s1*ax + s2*ay*az;
  R[8] = 1.f - s2*(ax*ax+ay*ay);
}

__device__ __forceinline__ void mm3(const float* A, const float* B, float* C){
  #pragma unroll
  for (int i=0;i<3;i++){
    float a0=A[3*i], a1=A[3*i+1], a2=A[3*i+2];
    #pragma unroll
    for (int l=0;l<3;l++)
      C[3*i+l] = a0*B[l] + a1*B[3+l] + a2*B[6+l];
  }
}

// ============================== MAIN PATH ==================================
// prep: blocks 0,1 = H tables (u-order + conj-reflected H2); blocks 2..129 = scan
__global__ __launch_bounds__(NTHR) void prep(
  const float* __restrict__ x, const float* __restrict__ A1, const float* __restrict__ A2,
  const float* fW1, const float* fb1p, const float* fW2, const float* fb2p,
  const float* fpW1, const float* fpb1, const float* fpW2, const float* fpb2,
  const float* gW1, const float* gb1, const float* gW2, const float* gb2,
  const float* gpW1, const float* gpb1, const float* gpW2, const float* gpb2,
  float* __restrict__ X, float2* __restrict__ Hcf, float2* __restrict__ Hcf2,
  float2* __restrict__ Hcg, float2* __restrict__ Hcg2)
{
  __shared__ float2 buf[BUFSZ];
  int tid = threadIdx.x;
  if (blockIdx.x < 2){
    const float *aW1,*ab1,*aW2,*ab2,*bW1,*bb1,*bW2,*bb2; float2 *outp, *outp2; int revd;
    if (blockIdx.x == 0){ aW1=fW1; ab1=fb1p; aW2=fW2; ab2=fb2p;
      bW1=fpW1; bb1=fpb1; bW2=fpW2; bb2=fpb2; outp=Hcf; outp2=Hcf2; revd=1; }
    else { aW1=gW1; ab1=gb1; aW2=gW2; ab2=gb2;
      bW1=gpW1; bb1=gpb1; bW2=gpW2; bb2=gpb2; outp=Hcg; outp2=Hcg2; revd=0; }
    float w1a[5],b1a[5],w2a[5],w1b[5],b1b[5],w2b[5];
    #pragma unroll
    for (int h=0;h<5;h++){
      w1a[h]=aW1[h]; b1a[h]=ab1[h]; w2a[h]=aW2[h];
      w1b[h]=bW1[h]; b1b[h]=bb1[h]; w2b[h]=bW2[h];
    }
    float cA = ab2[0], cB = bb2[0];
    const float nis = -3.14159265358979f / 4096.f;
    #pragma unroll
    for (int r = 0; r < 2048/NTHR; ++r){
      int j = tid + NTHR*r;
      float2 zz[2];
      #pragma unroll
      for (int h2 = 0; h2 < 2; ++h2){
        int n = j + 2048*h2;
        float t = revd ? (float)(TT-1-n) : (float)n;
        float va = cA, vb = cB;
        #pragma unroll
        for (int h=0;h<5;h++){
          va += w2a[h]*tanhf(w1a[h]*t + b1a[h]);
          vb += w2b[h]*tanhf(w1b[h]*t + b1b[h]);
        }
        zz[h2] = make_float2(va, vb);
      }
      float sn, cs; __sincosf(nis*(float)j, &sn, &cs);
      float2 wA = make_float2(cs, sn);
      float2 wB = make_float2(cs*cs - sn*sn, 2.f*cs*sn);
      float2 w3 = cmulf(wA, wB);
      float2 a = zz[0], b = zz[1];
      BREF(buf,j)      = cadd(a,b);
      BREF(buf,j+2048) = cmulf(csub(a,b), wB);
      BREF(buf,j+4096) = cmulf(wA, make_float2(a.x + b.y, a.y - b.x));
      BREF(buf,j+6144) = cmulf(w3, make_float2(a.x - b.y, a.y + b.x));
    }
    __syncthreads(); fwd_pass<512>(buf, tid);
    __syncthreads(); fwd_pass<128>(buf, tid);
    __syncthreads(); fwd_pass<32>(buf, tid);
    __syncthreads(); fwd_pass<8>(buf, tid);
    __syncthreads(); fwd_final8(buf, tid);
    __syncthreads();
    #pragma unroll
    for (int r=0;r<NFFT/NTHR;r++){
      int p = tid + NTHR*r;
      outp[p] = BREF(buf,p);
      int k  = (int)(__brev((unsigned)p) >> (32-LOGN));
      int kk = (NFFT - k) & (NFFT-1);
      int q  = (int)(__brev((unsigned)kk) >> (32-LOGN));
      float2 z = BREF(buf,q);
      outp2[p] = make_float2(z.x, -z.y);
    }
  } else {
    float* sc = (float*)buf;
    int b = blockIdx.x - 2, j = tid;
    float k1x = A1[7]-A1[5], k1y = A1[2]-A1[6], k1z = A1[3]-A1[1];
    float k2x = A2[7]-A2[5], k2y = A2[2]-A2[6], k2z = A2[3]-A2[1];
    float L[9] = {1,0,0, 0,1,0, 0,0,1};
    #pragma unroll 1
    for (int k=1;k<=8;k++){
      int t = 8*j + k;
      if (t < TT){
        float z0 = x[((size_t)b*TT + t)*2 + 0];
        float z1 = x[((size_t)b*TT + t)*2 + 1];
        float R[9];
        rot3(k1x*z0 + k2x*z1, k1y*z0 + k2y*z1, k1z*z0 + k2z*z1, R);
        float Cm[9]; mm3(L, R, Cm);
        #pragma unroll
        for (int m=0;m<9;m++) L[m] = Cm[m];
      }
    }
    #pragma unroll
    for (int m=0;m<9;m++) sc[(0*512 + j)*9 + m] = L[m];
    int cur = 0;
    for (int d=1; d<512; d<<=1){
      __syncthreads();
      float own[9], res[9];
      #pragma unroll
      for (int m=0;m<9;m++) own[m] = sc[(cur*512 + j)*9 + m];
      if (j >= d){
        float prev[9];
        #pragma unroll
        for (int m=0;m<9;m++) prev[m] = sc[(cur*512 + j - d)*9 + m];
        mm3(prev, own, res);
      } else {
        #pragma unroll
        for (int m=0;m<9;m++) res[m] = own[m];
      }
      #pragma unroll
      for (int m=0;m<9;m++) sc[((cur^1)*512 + j)*9 + m] = res[m];
      cur ^= 1;
    }
    __syncthreads();
    float Xc[9];
    if (j == 0){
      Xc[0]=1;Xc[1]=0;Xc[2]=0;Xc[3]=0;Xc[4]=1;Xc[5]=0;Xc[6]=0;Xc[7]=0;Xc[8]=1;
    } else {
      #pragma unroll
      for (int m=0;m<9;m++) Xc[m] = sc[(cur*512 + j - 1)*9 + m];
    }
    #pragma unroll
    for (int m=0;m<9;m++) X[((size_t)b*9 + m)*TT + 8*j] = Xc[m];
    #pragma unroll 1
    for (int k=1;k<8;k++){
      int t = 8*j + k;
      float z0 = x[((size_t)b*TT + t)*2 + 0];
      float z1 = x[((size_t)b*TT + t)*2 + 1];
      float R[9];
      rot3(k1x*z0 + k2x*z1, k1y*z0 + k2y*z1, k1z*z0 + k2z*z1, R);
      float Cm[9]; mm3(Xc, R, Cm);
      #pragma unroll
      for (int m=0;m<9;m++){ Xc[m] = Cm[m]; X[((size_t)b*9 + m)*TT + t] = Xc[m]; }
    }
  }
}

// convk6: R7's convk4 (radix-8 fills, v[8] working set -> no spills at VGPR 128)
// + R8's proven XOR swizzle on a linear 64 KB buffer (bank conflicts /12).
__global__ __launch_bounds__(NTHR, 2) void convk6(const float* __restrict__ X,
    const float2* __restrict__ Hcf, const float2* __restrict__ Hcf2,
    const float2* __restrict__ Hcg, const float2* __restrict__ Hcg2,
    float* __restrict__ tmp)
{
  __shared__ float2 buf[NFFT];
  int tid = threadIdx.x;
  int task = blockIdx.x;
  int b1i, c1, b2i, c2; bool cross;
  if (task < 384){
    int b = task/3, p = task % 3;
    b1i = b; b2i = b; cross = true;
    c1 = (p==0)?1:((p==1)?2:5);
    c2 = (p==0)?3:((p==1)?6:7);
  } else if (task < 512){
    int b = task - 384; b1i=b; b2i=b; c1=0; c2=4; cross=false;
  } else {
    int q = task - 512; b1i = 2*q; b2i = 2*q+1; c1=8; c2=8; cross=false;
  }
  const float* x1 = X + ((size_t)b1i*9 + c1)*TT;
  const float* x2 = X + ((size_t)b2i*9 + c2)*TT;

  // forward fill: spans (4096,2048), zero-pad aware
  {
    const float nis = -3.14159265358979f / 4096.f;
    #pragma unroll
    for (int r = 0; r < 2048/NTHR; ++r){
      int j = tid + NTHR*r;
      float2 a = make_float2(x1[j], x2[j]);
      float2 b = make_float2(x1[j+2048], x2[j+2048]);
      float sn, cs; __sincosf(nis*(float)j, &sn, &cs);
      float2 wA = make_float2(cs, sn);
      float2 wB = make_float2(cs*cs - sn*sn, 2.f*cs*sn);
      float2 w3 = cmulf(wA, wB);
      buf[SWZ(j)]      = cadd(a,b);
      buf[SWZ(j+2048)] = cmulf(csub(a,b), wB);
      buf[SWZ(j+4096)] = cmulf(wA, make_float2(a.x + b.y, a.y - b.x));
      buf[SWZ(j+6144)] = cmulf(w3, make_float2(a.x - b.y, a.y + b.x));
    }
  }
  __syncthreads(); fwd_passS<512>(buf, tid);
  __syncthreads(); fwd_passS<128>(buf, tid);
  __syncthreads(); fwd_passS<32>(buf, tid);
  __syncthreads(); fwd_passS<8>(buf, tid);
  __syncthreads();
  float2 zreg[16];
  fwd_final8_regS(buf, tid, zreg);   // own positions only -> no barrier needed

  // W1 = IFFT(Z*Hcf) = (x1*f - x2*fp) + i(x1*fp + x2*f)   (unnormalized)
  // W2 = IFFT(Z*Hcf2)= (x1*f + x2*fp) + i(x2*f - x1*fp)
  float2 W1[8];
  inv_zhS(buf, tid, zreg, Hcf, W1);
  __syncthreads();
  float2 W2[8];
  inv_zhS(buf, tid, zreg, Hcf2, W2);
  float a1[8], a2[8], bb1[8], bb2[8];   // N*(x1*f), N*(x2*f), N*(x1*fp), N*(x2*fp)
  #pragma unroll
  for (int e = 0; e < 8; ++e){
    a1[e]  = 0.5f*(W1[e].x + W2[e].x);
    a2[e]  = 0.5f*(W1[e].y + W2[e].y);
    bb1[e] = 0.5f*(W1[e].y - W2[e].y);
    bb2[e] = 0.5f*(W2[e].x - W1[e].x);
  }
  __syncthreads();
  float2 V1[8];
  inv_zhS(buf, tid, zreg, Hcg, V1);
  __syncthreads();
  float2 V2[8];
  inv_zhS(buf, tid, zreg, Hcg2, V2);   // zreg dead after this fill

  const float invN2 = (1.0f/NFFT)*(1.0f/NFFT);
  float* op1 = tmp + ((size_t)b1i*9 + c1)*TT;
  float* op2 = tmp + ((size_t)b2i*9 + c2)*TT;
  #pragma unroll
  for (int r = 0; r < 4; ++r){
    #pragma unroll
    for (int h = 0; h < 2; ++h){
      int e = 2*r + h;
      int s = tid + NTHR*r + h*2048;
      float c1v = 0.5f*(V1[e].x + V2[e].x);   // N*(x1*g)
      float c2v = 0.5f*(V1[e].y + V2[e].y);   // N*(x2*g)
      float d1  = 0.5f*(V1[e].y - V2[e].y);   // N*(x1*gp)
      float d2  = 0.5f*(V2[e].x - V1[e].x);   // N*(x2*gp)
      float Af1 = cross ? a2[e]  : a1[e];
      float Bf1 = cross ? bb2[e] : bb1[e];
      float Af2 = cross ? a1[e]  : a2[e];
      float Bf2 = cross ? bb1[e] : bb2[e];
      op1[s] = (Af1*c1v + Bf1*d1) * invN2;
      op2[s] = (Af2*c2v + Bf2*d2) * invN2;
    }
  }
}

// repack: (b,9,T) channel-major -> (b,T,9) interleaved, LDS-tiled
__global__ __launch_bounds__(256) void repack(const float* __restrict__ tmp,
                                              float* __restrict__ out){
  __shared__ float tile[9][264];
  int b  = blockIdx.x >> 4;
  int t0 = (blockIdx.x & 15) << 8;
  int tid = threadIdx.x;
  #pragma unroll
  for (int c = 0; c < 9; ++c)
    tile[c][tid] = tmp[((size_t)b*9 + c)*TT + t0 + tid];
  __syncthreads();
  size_t base = ((size_t)b*TT + t0)*9;
  #pragma unroll
  for (int k = 0; k < 9; ++k){
    int idx = tid + 256*k;
    out[base + idx] = tile[idx % 9][idx / 9];
  }
}

// ============================ FALLBACK (R1) ================================
__device__ void fft_dif_bitrev(float2* buf, int tid){
  const float PI = 3.14159265358979f;
  #pragma unroll 1
  for (int stage = 0; stage < LOGN; ++stage){
    int logspan = LOGN - 1 - stage;
    int span = 1 << logspan;
    float nis = -PI / (float)span;
    __syncthreads();
    #pragma unroll
    for (int r = 0; r < NFFT/2/NTHR; ++r){
      int j = tid + NTHR*r;
      int off = j & (span - 1);
      int i0 = ((j >> logspan) << (logspan + 1)) + off;
      int i1 = i0 + span;
      float2 a = buf[i0], b = buf[i1];
      float ang = nis * (float)off;
      float sn, cs;
      __sincosf(ang, &sn, &cs);
      float2 d = make_float2(a.x - b.x, a.y - b.y);
      buf[i0] = make_float2(a.x + b.x, a.y + b.y);
      buf[i1] = cmulf(d, make_float2(cs, sn));
    }
  }
  __syncthreads();
  #pragma unroll
  for (int r = 0; r < NFFT/NTHR; ++r){
    int p = tid + NTHR*r;
    int q = (int)(__brev((unsigned)p) >> (32 - LOGN));
    if (p < q){ float2 t = buf[p]; buf[p] = buf[q]; buf[q] = t; }
  }
  __syncthreads();
}

__global__ __launch_bounds__(NTHR) void hker_fb(
  const float* fW1, const float* fb1p, const float* fW2, const float* fb2p,
  const float* fpW1, const float* fpb1, const float* fpW2, const float* fpb2,
  const float* gW1, const float* gb1, const float* gW2, const float* gb2,
  const float* gpW1, const float* gpb1, const float* gpW2, const float* gpb2,
  float2* Hcf, float2* Hcg)
{
  __shared__ float2 buf[NFFT];
  int tid = threadIdx.x;
  const float *aW1,*ab1,*aW2,*ab2,*bW1,*bb1,*bW2,*bb2; float2* outp; int revd;
  if (blockIdx.x == 0){ aW1=fW1; ab1=fb1p; aW2=fW2; ab2=fb2p;
    bW1=fpW1; bb1=fpb1; bW2=fpW2; bb2=fpb2; outp=Hcf; revd=1; }
  else { aW1=gW1; ab1=gb1; aW2=gW2; ab2=gb2;
    bW1=gpW1; bb1=gpb1; bW2=gpW2; bb2=gpb2; outp=Hcg; revd=0; }
  float w1a[5],b1a[5],w2a[5],w1b[5],b1b[5],w2b[5];
  #pragma unroll
  for (int h=0;h<5;h++){
    w1a[h]=aW1[h]; b1a[h]=ab1[h]; w2a[h]=aW2[h];
    w1b[h]=bW1[h]; b1b[h]=bb1[h]; w2b[h]=bW2[h];
  }
  float cA = ab2[0], cB = bb2[0];
  for (int r=0;r<NFFT/NTHR;r++){
    int s = tid + NTHR*r;
    float2 v = make_float2(0.f, 0.f);
    if (s < TT){
      float t = revd ? (float)(TT-1-s) : (float)s;
      float va = cA, vb = cB;
      #pragma unroll
      for (int h=0;h<5;h++){
        va += w2a[h]*tanhf(w1a[h]*t + b1a[h]);
        vb += w2b[h]*tanhf(w1b[h]*t + b1b[h]);
      }
      v = make_float2(va, vb);
    }
    buf[s] = v;
  }
  fft_dif_bitrev(buf, tid);
  for (int r=0;r<NFFT/NTHR;r++){ int k = tid + NTHR*r; outp[k] = buf[k]; }
}

__global__ __launch_bounds__(256) void scank_fb(const float* __restrict__ x,
    const float* __restrict__ A1, const float* __restrict__ A2,
    float* __restrict__ X)
{
  __shared__ float sc[2][256][9];
  int b = blockIdx.x, j = threadIdx.x;
  float k1x = A1[7]-A1[5], k1y = A1[2]-A1[6], k1z = A1[3]-A1[1];
  float k2x = A2[7]-A2[5], k2y = A2[2]-A2[6], k2z = A2[3]-A2[1];
  float L[9] = {1,0,0, 0,1,0, 0,0,1};
  #pragma unroll 1
  for (int k=1;k<=16;k++){
    int t = 16*j + k;
    if (t < TT){
      float z0 = x[((size_t)b*TT + t)*2 + 0];
      float z1 = x[((size_t)b*TT + t)*2 + 1];
      float R[9];
      rot3(k1x*z0 + k2x*z1, k1y*z0 + k2y*z1, k1z*z0 + k2z*z1, R);
      float Cm[9]; mm3(L, R, Cm);
      #pragma unroll
      for (int m=0;m<9;m++) L[m] = Cm[m];
    }
  }
  #pragma unroll
  for (int m=0;m<9;m++) sc[0][j][m] = L[m];
  int cur = 0;
  for (int d=1; d<256; d<<=1){
    __syncthreads();
    float own[9], res[9];
    #pragma unroll
    for (int m=0;m<9;m++) own[m] = sc[cur][j][m];
    if (j >= d){
      float prev[9];
      #pragma unroll
      for (int m=0;m<9;m++) prev[m] = sc[cur][j-d][m];
      mm3(prev, own, res);
    } else {
      #pragma unroll
      for (int m=0;m<9;m++) res[m] = own[m];
    }
    #pragma unroll
    for (int m=0;m<9;m++) sc[cur^1][j][m] = res[m];
    cur ^= 1;
  }
  __syncthreads();
  float Xc[9];
  if (j == 0){
    Xc[0]=1;Xc[1]=0;Xc[2]=0;Xc[3]=0;Xc[4]=1;Xc[5]=0;Xc[6]=0;Xc[7]=0;Xc[8]=1;
  } else {
    #pragma unroll
    for (int m=0;m<9;m++) Xc[m] = sc[cur][j-1][m];
  }
  #pragma unroll
  for (int m=0;m<9;m++) X[((size_t)b*9 + m)*TT + 16*j] = Xc[m];
  #pragma unroll 1
  for (int k=1;k<16;k++){
    int t = 16*j + k;
    float z0 = x[((size_t)b*TT + t)*2 + 0];
    float z1 = x[((size_t)b*TT + t)*2 + 1];
    float R[9];
    rot3(k1x*z0 + k2x*z1, k1y*z0 + k2y*z1, k1z*z0 + k2z*z1, R);
    float Cm[9]; mm3(Xc, R, Cm);
    #pragma unroll
    for (int m=0;m<9;m++){ Xc[m] = Cm[m]; X[((size_t)b*9 + m)*TT + t] = Xc[m]; }
  }
}

__global__ __launch_bounds__(NTHR) void convk_fb(const float* __restrict__ X,
    const float2* __restrict__ Hcf, const float2* __restrict__ Hcg,
    float* __restrict__ out)
{
  __shared__ float2 buf[NFFT];
  __shared__ float2 fb1[NFFT/2 + 2];
  __shared__ float2 fb2[NFFT/2 + 2];
  int tid = threadIdx.x;
  int task = blockIdx.x;
  int b1i, c1, b2i, c2; bool cross;
  if (task < 384){
    int b = task/3, p = task % 3;
    b1i = b; b2i = b; cross = true;
    c1 = (p==0)?1:((p==1)?2:5);
    c2 = (p==0)?3:((p==1)?6:7);
  } else if (task < 512){
    int b = task - 384; b1i=b; b2i=b; c1=0; c2=4; cross=false;
  } else {
    int q = task - 512; b1i = 2*q; b2i = 2*q+1; c1=8; c2=8; cross=false;
  }
  const float* x1 = X + ((size_t)b1i*9 + c1)*TT;
  const float* x2 = X + ((size_t)b2i*9 + c2)*TT;
  #pragma unroll
  for (int r=0;r<NFFT/NTHR;r++){
    int s = tid + NTHR*r;
    float2 v = make_float2(0.f,0.f);
    if (s < TT){ v.x = x1[s]; v.y = x2[s]; }
    buf[s] = v;
  }
  fft_dif_bitrev(buf, tid);
  for (int k = tid; k <= NFFT/2; k += NTHR){
    int kk = (NFFT - k) & (NFFT - 1);
    float2 zk = buf[k], zn = buf[kk];
    fb1[k] = make_float2(0.5f*(zk.x + zn.x), 0.5f*(zk.y - zn.y));
    fb2[k] = make_float2(0.5f*(zk.y + zn.y), 0.5f*(zn.x - zk.x));
  }
  __syncthreads();
  const float invN2 = (1.0f/NFFT)*(1.0f/NFFT);
  #pragma unroll 1
  for (int pass = 0; pass < 2; ++pass){
    const float2* fA = (pass==0) ? (cross ? fb2 : fb1) : (cross ? fb1 : fb2);
    const float2* fG = (pass==0) ? fb1 : fb2;
    int ob = (pass==0) ? b1i : b2i;
    int oc = (pass==0) ? c1 : c2;
    #pragma unroll
    for (int r=0;r<NFFT/NTHR;r++){
      int k = tid + NTHR*r;
      float2 F;
      if (k <= NFFT/2) F = fA[k];
      else { float2 g = fA[NFFT-k]; F = make_float2(g.x, -g.y); }
      float2 P = cmulf(F, Hcf[k]);
      buf[k] = make_float2(P.x, -P.y);
    }
    fft_dif_bitrev(buf, tid);
    float rA[8], rB[8];
    #pragma unroll
    for (int r=0;r<8;r++){
      int s = tid + NTHR*r;
      rA[r] = buf[s].x;
      rB[r] = -buf[s].y;
    }
    #pragma unroll
    for (int r=0;r<NFFT/NTHR;r++){
      int k = tid + NTHR*r;
      float2 F;
      if (k <= NFFT/2) F = fG[k];
      else { float2 g = fG[NFFT-k]; F = make_float2(g.x, -g.y); }
      float2 P = cmulf(F, Hcg[k]);
      buf[k] = make_float2(P.x, -P.y);
    }
    fft_dif_bitrev(buf, tid);
    #pragma unroll
    for (int r=0;r<8;r++){
      int s = tid + NTHR*r;
      float AB = buf[s].x, BB = -buf[s].y;
      out[((size_t)ob*TT + s)*9 + oc] = (rA[r]*AB + rB[r]*BB) * invN2;
    }
  }
}

// ================================ HOST =====================================
extern "C" void kernel_launch(void* const* d_in, const int* in_sizes, int n_in,
                              void* d_out, int out_size, void* d_ws, size_t ws_size,
                              hipStream_t stream){
  const float* x  = (const float*)d_in[0];
  const float* A1 = (const float*)d_in[1];
  const float* A2 = (const float*)d_in[2];
  const float* P[16];
  for (int i=0;i<16;i++) P[i] = (const float*)d_in[3+i];

  size_t xbytes = (size_t)BS*9*TT*sizeof(float);               // 18,874,368
  size_t hbytes = (size_t)NFFT*sizeof(float2);                 // 65,536
  float*  Xb   = (float*)d_ws;
  float2* Hcf  = (float2*)((char*)d_ws + xbytes);
  float2* Hcf2 = Hcf + NFFT;
  float2* Hcg  = Hcf + 2*NFFT;
  float2* Hcg2 = Hcf + 3*NFFT;
  float*  tmp  = (float*)((char*)d_ws + xbytes + 4*hbytes);
  size_t need = xbytes + 4*hbytes + xbytes;

  if (ws_size >= need){
    prep<<<2 + BS, NTHR, 0, stream>>>(x, A1, A2,
        P[0],P[1],P[2],P[3],P[4],P[5],P[6],P[7],
        P[8],P[9],P[10],P[11],P[12],P[13],P[14],P[15],
        Xb, Hcf, Hcf2, Hcg, Hcg2);
    convk6<<<NTASK, NTHR, 0, stream>>>(Xb, Hcf, Hcf2, Hcg, Hcg2, tmp);
    repack<<<BS*16, 256, 0, stream>>>(tmp, (float*)d_out);
  } else {
    hker_fb<<<2, NTHR, 0, stream>>>(P[0],P[1],P[2],P[3],P[4],P[5],P[6],P[7],
        P[8],P[9],P[10],P[11],P[12],P[13],P[14],P[15], Hcf, Hcg);
    scank_fb<<<BS, 256, 0, stream>>>(x, A1, A2, Xb);
    convk_fb<<<NTASK, NTHR, 0, stream>>>(Xb, Hcf, Hcg, (float*)d_out);
  }
}